// Round 7
// baseline (1294.657 us; speedup 1.0000x reference)
//
#include <hip/hip_runtime.h>
#include <hip/hip_bf16.h>

#define N_NODES 100000
#define N_RELS  4
#define N_EDGES 250000
#define TOTAL_E (N_RELS * N_EDGES)
#define NR      (N_RELS * N_NODES)
#define D       128
#define CSR_BLKS 1024
#define SCAN_BLKS 391   // ceil(NR/1024)

typedef __attribute__((ext_vector_type(8))) short bf16x8;
typedef __attribute__((ext_vector_type(4))) float f32x4;

__device__ __forceinline__ float b2f(short u) {
    unsigned int x = ((unsigned int)(unsigned short)u) << 16;
    return __builtin_bit_cast(float, x);
}
__device__ __forceinline__ unsigned short f2b(float f) {
    unsigned int u = __builtin_bit_cast(unsigned int, f);
    return (unsigned short)((u + 0x7fffu + ((u >> 16) & 1u)) >> 16);  // RNE
}

// ---------------------------------------------------------------------------
// software grid barrier (all CSR_BLKS blocks co-resident by construction)
// ---------------------------------------------------------------------------
__device__ __forceinline__ void grid_barrier(int* cnt, int* gen) {
    __syncthreads();
    __threadfence();   // release: publish this block's writes (agent scope)
    if (threadIdx.x == 0) {
        int my = __hip_atomic_load(gen, __ATOMIC_RELAXED, __HIP_MEMORY_SCOPE_AGENT);
        int t  = __hip_atomic_fetch_add(cnt, 1, __ATOMIC_ACQ_REL, __HIP_MEMORY_SCOPE_AGENT);
        if (t == CSR_BLKS - 1) {
            __hip_atomic_store(cnt, 0, __ATOMIC_RELAXED, __HIP_MEMORY_SCOPE_AGENT);
            __hip_atomic_fetch_add(gen, 1, __ATOMIC_RELEASE, __HIP_MEMORY_SCOPE_AGENT);
        } else {
            while (__hip_atomic_load(gen, __ATOMIC_ACQUIRE, __HIP_MEMORY_SCOPE_AGENT) == my)
                __builtin_amdgcn_s_sleep(8);
        }
    }
    __syncthreads();
    __threadfence();   // acquire: invalidate L1 so others' writes are visible
}

// ---------------------------------------------------------------------------
// ONE-dispatch prep + CSR build:
//  ph0: zero deg | x->bf16 | W->bf16 W^T   (independent, grid-strided)
//  ph1: hist   ph2: scan1   ph3: addoff(+sentinel,cursor)   ph4: fill
// ---------------------------------------------------------------------------
__global__ __launch_bounds__(256, 4) void csr_prep_kernel(
    const float* __restrict__ x, const float* __restrict__ weight,
    const float* __restrict__ loop_w, const int* __restrict__ src,
    const int* __restrict__ dst,
    unsigned short* __restrict__ xb, unsigned short* __restrict__ wT,
    int* __restrict__ deg, int* __restrict__ off, int* __restrict__ cursor,
    int* __restrict__ aux, int* __restrict__ sorted_src,
    int* __restrict__ bar_cnt, int* __restrict__ bar_gen)
{
    const int t   = threadIdx.x;
    const int gid = blockIdx.x * 256 + t;
    const int NT  = CSR_BLKS * 256;
    __shared__ int s[256];

    // ---- phase 0 ----
    for (int i = gid; i < NR; i += NT) deg[i] = 0;
    for (int i = gid; i < N_NODES * D / 8; i += NT) {
        float4 v0 = *reinterpret_cast<const float4*>(x + (size_t)i * 8);
        float4 v1 = *reinterpret_cast<const float4*>(x + (size_t)i * 8 + 4);
        bf16x8 o;
        o[0] = (short)f2b(v0.x); o[1] = (short)f2b(v0.y);
        o[2] = (short)f2b(v0.z); o[3] = (short)f2b(v0.w);
        o[4] = (short)f2b(v1.x); o[5] = (short)f2b(v1.y);
        o[6] = (short)f2b(v1.z); o[7] = (short)f2b(v1.w);
        *reinterpret_cast<bf16x8*>(xb + (size_t)i * 8) = o;
    }
    for (int i = gid; i < 5 * D * D; i += NT) {
        int mat = i >> 14, n = (i >> 7) & 127, k = i & 127;
        const float* srcm = (mat < 4) ? (weight + (size_t)mat * D * D) : loop_w;
        wT[i] = f2b(srcm[k * D + n]);
    }
    grid_barrier(bar_cnt, bar_gen);

    // ---- phase 1: histogram ----
    for (int i = gid; i < TOTAL_E; i += NT) {
        int rel = i / N_EDGES;
        atomicAdd(&deg[rel * N_NODES + dst[i]], 1);
    }
    grid_barrier(bar_cnt, bar_gen);

    // ---- phase 2: per-chunk exclusive scan (chunk = 1024 entries) ----
    if (blockIdx.x < SCAN_BLKS) {
        int base = blockIdx.x * 1024 + t * 4;
        int v[4]; int sum = 0;
        #pragma unroll
        for (int j = 0; j < 4; ++j) {
            v[j] = (base + j < NR) ? deg[base + j] : 0;
            sum += v[j];
        }
        s[t] = sum;
        for (int o = 1; o < 256; o <<= 1) {
            __syncthreads();
            int u = (t >= o) ? s[t - o] : 0;
            __syncthreads();
            s[t] += u;
        }
        __syncthreads();
        int excl = (t > 0) ? s[t - 1] : 0;
        #pragma unroll
        for (int j = 0; j < 4; ++j) {
            if (base + j < NR) off[base + j] = excl;
            excl += v[j];
        }
        if (t == 255) aux[blockIdx.x] = s[255];
    }
    grid_barrier(bar_cnt, bar_gen);

    // ---- phase 3: add chunk prefix, mirror cursor, sentinel ----
    if (blockIdx.x < SCAN_BLKS) {
        if (blockIdx.x == 0 && t == 0) off[NR] = TOTAL_E;
        int part = 0;
        for (int j = t; j < (int)blockIdx.x; j += 256) part += aux[j];
        s[t] = part;
        for (int o = 128; o > 0; o >>= 1) {
            __syncthreads();
            if (t < o) s[t] += s[t + o];
        }
        __syncthreads();
        int S = s[0];
        int base = blockIdx.x * 1024 + t * 4;
        #pragma unroll
        for (int j = 0; j < 4; ++j) {
            int i = base + j;
            if (i < NR) { int v2 = off[i] + S; off[i] = v2; cursor[i] = v2; }
        }
    }
    grid_barrier(bar_cnt, bar_gen);

    // ---- phase 4: fill sorted_src ----
    for (int i = gid; i < TOTAL_E; i += NT) {
        int rel = i / N_EDGES;
        int pos = atomicAdd(&cursor[rel * N_NODES + dst[i]], 1);
        sorted_src[pos] = src[i];
    }
}

// ---------------------------------------------------------------------------
// Fused MFMA kernel: 32-row tile, 256 threads (4 waves x 32 output cols).
// ALL 4 relations gathered CONCURRENTLY (4 independent chains per thread,
// predicated) into 4 swizzled LDS A-tiles; ONE barrier; then 4 MFMA phases
// + self-loop + epilogue with no further syncs.
// ---------------------------------------------------------------------------
__global__ __launch_bounds__(256) void fused_gemm_mfma(
    const unsigned short* __restrict__ xb,   // [N,128] bf16
    const unsigned short* __restrict__ wT,   // [5,128,128] bf16 n-major
    const float* __restrict__ conv_bias,     // [4,128]
    const float* __restrict__ node_bias,     // [128]
    const int* __restrict__ off,             // [4*N + 1] (sentinel)
    const int* __restrict__ sorted_src,      // [1M]
    float* __restrict__ out)                 // [N,128] f32
{
    __shared__ __align__(16) unsigned char sIn[4 * 32 * 256];   // 32 KB

    const int tid  = threadIdx.x;
    const int row0 = blockIdx.x * 32;
    const int wid  = tid >> 6;
    const int lane = tid & 63;
    const int l15  = lane & 15;
    const int l4   = lane >> 4;
    const int swA  = (l15 & 7) << 4;

    // gather mapping: 8 threads/row, 16 cols (32 B) each
    const int gr  = tid >> 3;
    const int gc  = tid & 7;
    const int gsw = (gr & 7) << 4;

    // ---- prefetch all 4 phase ranges (8 independent loads) ----
    int begs[4], ends[4];
    #pragma unroll
    for (int p = 0; p < 4; ++p) {
        int node = p * N_NODES + row0 + gr;
        begs[p] = off[node];
        ends[p] = off[node + 1];
    }

    // ---- 4-way concurrent CSR gather ----
    {
        const unsigned short* xcol = xb + gc * 16;
        float a[4][16];
        #pragma unroll
        for (int p = 0; p < 4; ++p)
            #pragma unroll
            for (int j = 0; j < 16; ++j) a[p][j] = 0.f;

        int e0 = begs[0], e1 = begs[1], e2 = begs[2], e3 = begs[3];
        const int f0 = ends[0], f1 = ends[1], f2 = ends[2], f3 = ends[3];

#define GATH(P, eP, fP)                                                        \
        if (eP < fP) {                                                         \
            int sn = sorted_src[eP];                                           \
            const bf16x8* pp =                                                 \
                reinterpret_cast<const bf16x8*>(xcol + (size_t)sn * D);        \
            bf16x8 u = pp[0], v = pp[1];                                       \
            _Pragma("unroll")                                                  \
            for (int j = 0; j < 8; ++j) {                                      \
                a[P][j]     += b2f(u[j]);                                      \
                a[P][8 + j] += b2f(v[j]);                                      \
            }                                                                  \
            ++eP;                                                              \
        }

        while ((e0 < f0) || (e1 < f1) || (e2 < f2) || (e3 < f3)) {
            GATH(0, e0, f0)
            GATH(1, e1, f1)
            GATH(2, e2, f2)
            GATH(3, e3, f3)
        }
#undef GATH

        // normalize + convert + write 4 swizzled LDS tiles
        #pragma unroll
        for (int p = 0; p < 4; ++p) {
            float scl = 1.0f / fmaxf((float)(ends[p] - begs[p]), 1.0f);
            bf16x8 o0, o1;
            #pragma unroll
            for (int j = 0; j < 8; ++j) {
                o0[j] = (short)f2b(a[p][j] * scl);
                o1[j] = (short)f2b(a[p][8 + j] * scl);
            }
            int base = p * 8192 + gr * 256;
            *reinterpret_cast<bf16x8*>(&sIn[base + ((gc * 32) ^ gsw)])      = o0;
            *reinterpret_cast<bf16x8*>(&sIn[base + ((gc * 32 + 16) ^ gsw)]) = o1;
        }
    }
    __syncthreads();   // the ONLY block-wide barrier

    // ---- 4 MFMA phases, no further syncs ----
    f32x4 acc_mean[2][2];
    #pragma unroll
    for (int m = 0; m < 2; ++m)
        #pragma unroll
        for (int n = 0; n < 2; ++n)
            acc_mean[m][n] = (f32x4){0.f, 0.f, 0.f, 0.f};

    #pragma unroll
    for (int phase = 0; phase < 4; ++phase) {
        const unsigned short* wp = wT + (size_t)phase * D * D;
        f32x4 acc[2][2];
        #pragma unroll
        for (int m = 0; m < 2; ++m)
            #pragma unroll
            for (int n = 0; n < 2; ++n)
                acc[m][n] = (f32x4){0.f, 0.f, 0.f, 0.f};

        #pragma unroll
        for (int s = 0; s < 4; ++s) {
            int kb = s * 64 + l4 * 16;
            bf16x8 a0 = *reinterpret_cast<const bf16x8*>(
                &sIn[phase * 8192 + l15 * 256 + (kb ^ swA)]);
            bf16x8 a1 = *reinterpret_cast<const bf16x8*>(
                &sIn[phase * 8192 + (16 + l15) * 256 + (kb ^ swA)]);
            bf16x8 b0 = *reinterpret_cast<const bf16x8*>(
                wp + (wid * 32 + l15) * D + s * 32 + l4 * 8);
            bf16x8 b1 = *reinterpret_cast<const bf16x8*>(
                wp + (wid * 32 + 16 + l15) * D + s * 32 + l4 * 8);
            acc[0][0] = __builtin_amdgcn_mfma_f32_16x16x32_bf16(a0, b0, acc[0][0], 0, 0, 0);
            acc[0][1] = __builtin_amdgcn_mfma_f32_16x16x32_bf16(a0, b1, acc[0][1], 0, 0, 0);
            acc[1][0] = __builtin_amdgcn_mfma_f32_16x16x32_bf16(a1, b0, acc[1][0], 0, 0, 0);
            acc[1][1] = __builtin_amdgcn_mfma_f32_16x16x32_bf16(a1, b1, acc[1][1], 0, 0, 0);
        }

        float b0 = conv_bias[phase * D + wid * 32 + l15];
        float b1 = conv_bias[phase * D + wid * 32 + 16 + l15];
        #pragma unroll
        for (int m = 0; m < 2; ++m)
            #pragma unroll
            for (int j = 0; j < 4; ++j) {
                acc_mean[m][0][j] += 0.25f * fmaxf(acc[m][0][j] + b0, 0.f);
                acc_mean[m][1][j] += 0.25f * fmaxf(acc[m][1][j] + b1, 0.f);
            }
    }

    // ---- self-loop: A-frags direct from global xb ----
    f32x4 acc_self[2][2];
    {
        const unsigned short* wp = wT + (size_t)4 * D * D;
        #pragma unroll
        for (int m = 0; m < 2; ++m)
            #pragma unroll
            for (int n = 0; n < 2; ++n)
                acc_self[m][n] = (f32x4){0.f, 0.f, 0.f, 0.f};

        #pragma unroll
        for (int s = 0; s < 4; ++s) {
            bf16x8 a0 = *reinterpret_cast<const bf16x8*>(
                xb + (size_t)(row0 + l15) * D + s * 32 + l4 * 8);
            bf16x8 a1 = *reinterpret_cast<const bf16x8*>(
                xb + (size_t)(row0 + 16 + l15) * D + s * 32 + l4 * 8);
            bf16x8 b0 = *reinterpret_cast<const bf16x8*>(
                wp + (wid * 32 + l15) * D + s * 32 + l4 * 8);
            bf16x8 b1 = *reinterpret_cast<const bf16x8*>(
                wp + (wid * 32 + 16 + l15) * D + s * 32 + l4 * 8);
            acc_self[0][0] = __builtin_amdgcn_mfma_f32_16x16x32_bf16(a0, b0, acc_self[0][0], 0, 0, 0);
            acc_self[0][1] = __builtin_amdgcn_mfma_f32_16x16x32_bf16(a0, b1, acc_self[0][1], 0, 0, 0);
            acc_self[1][0] = __builtin_amdgcn_mfma_f32_16x16x32_bf16(a1, b0, acc_self[1][0], 0, 0, 0);
            acc_self[1][1] = __builtin_amdgcn_mfma_f32_16x16x32_bf16(a1, b1, acc_self[1][1], 0, 0, 0);
        }
        float b0 = node_bias[wid * 32 + l15];
        float b1 = node_bias[wid * 32 + 16 + l15];
        #pragma unroll
        for (int m = 0; m < 2; ++m)
            #pragma unroll
            for (int j = 0; j < 4; ++j) {
                acc_self[m][0][j] += b0;
                acc_self[m][1][j] += b1;
            }
    }

    // ---- final epilogue: relu(silu(mean) + self) ----
    #pragma unroll
    for (int m = 0; m < 2; ++m)
        #pragma unroll
        for (int n = 0; n < 2; ++n)
            #pragma unroll
            for (int j = 0; j < 4; ++j) {
                float mn = acc_mean[m][n][j];                 // >= 0
                float sl = mn / (1.0f + __expf(-mn));
                float v  = fmaxf(sl + acc_self[m][n][j], 0.f);
                int row = row0 + m * 16 + l4 * 4 + j;
                int col = wid * 32 + n * 16 + l15;
                out[(size_t)row * D + col] = v;
            }
}

// ---------------------------------------------------------------------------
extern "C" void kernel_launch(void* const* d_in, const int* in_sizes, int n_in,
                              void* d_out, int out_size, void* d_ws, size_t ws_size,
                              hipStream_t stream) {
    const float* x         = (const float*)d_in[0];
    const float* weight    = (const float*)d_in[1];
    const float* conv_bias = (const float*)d_in[2];
    const float* loop_w    = (const float*)d_in[3];
    const float* node_bias = (const float*)d_in[4];
    const int*   src       = (const int*)d_in[5];
    const int*   dst       = (const int*)d_in[6];
    float* out = (float*)d_out;

    // ws layout (bytes)
    char* w = (char*)d_ws;
    int* deg            = (int*)(w);                      // 1.6 MB
    int* off            = (int*)(w + 1600000);            // 1.6 MB + sentinel
    int* cursor         = (int*)(w + 3200008);            // 1.6 MB
    int* aux            = (int*)(w + 4800008);            // 1564 B
    int* bar            = (int*)(w + 4801800);            // 8 B (cnt, gen)
    int* sorted_src     = (int*)(w + 4802056);            // 4 MB
    unsigned short* xb  = (unsigned short*)(w + 8802056); // 25.6 MB
    unsigned short* wT  = (unsigned short*)(w + 8802056 + (size_t)N_NODES * D * 2);

    hipMemsetAsync(bar, 0, 8, stream);
    csr_prep_kernel<<<CSR_BLKS, 256, 0, stream>>>(
        x, weight, loop_w, src, dst, xb, wT,
        deg, off, cursor, aux, sorted_src, bar, bar + 1);
    fused_gemm_mfma<<<N_NODES / 32, 256, 0, stream>>>(
        xb, wT, conv_bias, node_bias, off, sorted_src, out);
}